// Round 1
// baseline (185.645 us; speedup 1.0000x reference)
//
#include <hip/hip_runtime.h>

#define N_NODES 4096
#define C 256
#define NH 4
#define CH 64
#define ROWS 8          // rows per block in k_feats
#define TI 32           // i-rows per wave tile in k_attn
#define TJ 32           // K-step (j) per MFMA round
#define JSPLIT 4
#define JSLICE (N_NODES / JSPLIT)
#define LDSTRIDE 40     // ushorts per LDS featsT row: 32 used + 8 pad (80B, bank-friendly)

typedef float f32x4 __attribute__((ext_vector_type(4)));
typedef __bf16 b16x8 __attribute__((ext_vector_type(8)));
typedef unsigned short u16x8 __attribute__((ext_vector_type(8)));

__device__ inline unsigned short f2bf(float f) {
  unsigned u = __float_as_uint(f);
  u += 0x7fffu + ((u >> 16) & 1u);   // RNE
  return (unsigned short)(u >> 16);
}

__device__ inline float fast_exp2(float x) {
#if __has_builtin(__builtin_amdgcn_exp2f)
  return __builtin_amdgcn_exp2f(x);
#else
  return exp2f(x);
#endif
}

// ---------------- Kernel 1: feats = X@W + b (fp32), src/dst, featsT (bf16, transposed)
__global__ __launch_bounds__(256) void k_feats(
    const float* __restrict__ nf, const float* __restrict__ W,
    const float* __restrict__ bias, const float* __restrict__ av,
    unsigned short* __restrict__ featsT, float* __restrict__ srcv,
    float* __restrict__ dstT) {
  __shared__ float xs[ROWS][C];
  const int i0 = blockIdx.x * ROWS;
  const int c = threadIdx.x;
#pragma unroll
  for (int r = 0; r < ROWS; ++r) xs[r][c] = nf[(size_t)(i0 + r) * C + c];
  __syncthreads();

  float acc[ROWS];
  const float bc = bias[c];
#pragma unroll
  for (int r = 0; r < ROWS; ++r) acc[r] = bc;

  for (int k4 = 0; k4 < C / 4; ++k4) {
    float4 xv[ROWS];
#pragma unroll
    for (int r = 0; r < ROWS; ++r) xv[r] = ((const float4*)xs[r])[k4];
#pragma unroll
    for (int kk = 0; kk < 4; ++kk) {
      const float wv = W[(size_t)(k4 * 4 + kk) * C + c];
#pragma unroll
      for (int r = 0; r < ROWS; ++r)
        acc[r] = fmaf(((const float*)&xv[r])[kk], wv, acc[r]);
    }
  }

  const int h = c >> 6, lane = c & 63;
  const float as = av[h * 2 * CH + lane];
  const float ad = av[h * 2 * CH + CH + lane];
  unsigned pk[4];
#pragma unroll
  for (int r = 0; r < ROWS; ++r) {
    const float f = acc[r];
    const unsigned short fb = f2bf(f);
    if (r & 1) pk[r >> 1] |= ((unsigned)fb) << 16; else pk[r >> 1] = (unsigned)fb;
    float p = f * as, d = f * ad;
#pragma unroll
    for (int m = 32; m; m >>= 1) {
      p += __shfl_xor(p, m);
      d += __shfl_xor(d, m);
    }
    if (lane == 0) {
      srcv[(size_t)(i0 + r) * NH + h] = p;       // src[i,h]
      dstT[(size_t)h * N_NODES + i0 + r] = d;    // dstT[h][j]
    }
  }
  uint4 st; st.x = pk[0]; st.y = pk[1]; st.z = pk[2]; st.w = pk[3];
  *((uint4*)(featsT + (size_t)c * N_NODES + i0)) = st;  // featsT[c][i0..i0+7]
}

// ---------------- Kernel 2: masked-softmax attention + PV via MFMA (partial over j-slice)
__global__ __launch_bounds__(256, 2) void k_attn(
    const int* __restrict__ adj, const unsigned short* __restrict__ featsT,
    const float* __restrict__ srcv, const float* __restrict__ dstT,
    float* __restrict__ pacc, float* __restrict__ lpart) {
  __shared__ unsigned short sf[C * LDSTRIDE];
  const int slice = blockIdx.x;          // j-slice
  const int i0 = blockIdx.y * TI;        // row tile base
  const int h = threadIdx.x >> 6;        // wave = head
  const int lane = threadIdx.x & 63;
  const int q = lane >> 4, n = lane & 15;

  // global per-head max of dst (safe softmax shift; j-independent so slices add)
  float dm = -1e30f;
  const float4* d4 = (const float4*)(dstT + (size_t)h * N_NODES);
  for (int it = 0; it < N_NODES / 256; ++it) {
    float4 v = d4[it * 64 + lane];
    dm = fmaxf(dm, fmaxf(fmaxf(v.x, v.y), fmaxf(v.z, v.w)));
  }
#pragma unroll
  for (int m = 32; m; m >>= 1) dm = fmaxf(dm, __shfl_xor(dm, m));

  const float LOG2E = 1.4426950408889634f;
  const float s0 = srcv[(size_t)(i0 + n) * NH + h];
  const float s1 = srcv[(size_t)(i0 + 16 + n) * NH + h];
  const float m20 = fmaxf(s0 + dm, 0.2f * (s0 + dm)) * LOG2E;  // leaky(s+Dmax)*log2e
  const float m21 = fmaxf(s1 + dm, 0.2f * (s1 + dm)) * LOG2E;

  const f32x4 zero = {0.f, 0.f, 0.f, 0.f};
  f32x4 acc[2][4];
#pragma unroll
  for (int t = 0; t < 2; ++t)
#pragma unroll
    for (int g = 0; g < 4; ++g) acc[t][g] = zero;
  float l0 = 0.f, l1 = 0.f;

  const int jbase = slice * JSLICE;
  for (int jt = 0; jt < JSLICE / TJ; ++jt) {
    const int j0 = jbase + jt * TJ;
    __syncthreads();
    {  // stage featsT[:, j0:j0+32] -> LDS (row = channel, padded stride)
      const int t = threadIdx.x;
      const uint4* gp = (const uint4*)(featsT + (size_t)t * N_NODES + j0);
      uint4* lp = (uint4*)(sf + t * LDSTRIDE);
      uint4 w0 = gp[0], w1 = gp[1], w2 = gp[2], w3 = gp[3];
      lp[0] = w0; lp[1] = w1; lp[2] = w2; lp[3] = w3;
    }
    __syncthreads();

    // dst values for this wave's 8 k-positions (k = q*8+jj)
    float4 dA = *(const float4*)(dstT + (size_t)h * N_NODES + j0 + q * 8);
    float4 dB = *(const float4*)(dstT + (size_t)h * N_NODES + j0 + q * 8 + 4);
    const int4* ap0 = (const int4*)(adj + (size_t)(i0 + n) * N_NODES + j0 + q * 8);
    const int4* ap1 = (const int4*)(adj + (size_t)(i0 + 16 + n) * N_NODES + j0 + q * 8);
    int4 a00 = ap0[0], a01 = ap0[1];
    int4 a10 = ap1[0], a11 = ap1[1];

    float dv[8] = {dA.x, dA.y, dA.z, dA.w, dB.x, dB.y, dB.z, dB.w};
    int ai0[8] = {a00.x, a00.y, a00.z, a00.w, a01.x, a01.y, a01.z, a01.w};
    int ai1[8] = {a10.x, a10.y, a10.z, a10.w, a11.x, a11.y, a11.z, a11.w};

    u16x8 ua0, ua1;
#pragma unroll
    for (int jj = 0; jj < 8; ++jj) {
      float x0 = s0 + dv[jj];
      float e0 = fast_exp2(fmaf(fmaxf(x0, 0.2f * x0), LOG2E, -m20));
      e0 = ai0[jj] ? e0 : 0.0f;
      l0 += e0;
      ua0[jj] = f2bf(e0);
      float x1 = s1 + dv[jj];
      float e1 = fast_exp2(fmaf(fmaxf(x1, 0.2f * x1), LOG2E, -m21));
      e1 = ai1[jj] ? e1 : 0.0f;
      l1 += e1;
      ua1[jj] = f2bf(e1);
    }
    b16x8 av0 = __builtin_bit_cast(b16x8, ua0);
    b16x8 av1 = __builtin_bit_cast(b16x8, ua1);
#pragma unroll
    for (int g = 0; g < 4; ++g) {
      u16x8 bw = *(const u16x8*)(sf + (h * CH + g * 16 + n) * LDSTRIDE + q * 8);
      b16x8 bv = __builtin_bit_cast(b16x8, bw);
      acc[0][g] = __builtin_amdgcn_mfma_f32_16x16x32_bf16(av0, bv, acc[0][g], 0, 0, 0);
      acc[1][g] = __builtin_amdgcn_mfma_f32_16x16x32_bf16(av1, bv, acc[1][g], 0, 0, 0);
    }
  }

  // l: sum across the 4 quads (each held different k's)
  l0 += __shfl_xor(l0, 16); l0 += __shfl_xor(l0, 32);
  l1 += __shfl_xor(l1, 16); l1 += __shfl_xor(l1, 32);
  if (q == 0) {
    lpart[((size_t)slice * N_NODES + i0 + n) * NH + h] = l0;
    lpart[((size_t)slice * N_NODES + i0 + 16 + n) * NH + h] = l1;
  }
#pragma unroll
  for (int t = 0; t < 2; ++t)
#pragma unroll
    for (int g = 0; g < 4; ++g)
#pragma unroll
      for (int r = 0; r < 4; ++r) {
        const int row = i0 + t * 16 + q * 4 + r;   // C/D layout: row = quad*4+reg
        const int col = h * CH + g * 16 + n;       // col = lane&15
        pacc[((size_t)slice * N_NODES + row) * C + col] = acc[t][g][r];
      }
}

// ---------------- Kernel 3: combine j-slices, divide by softmax denominator
__global__ __launch_bounds__(256) void k_final(
    const float* __restrict__ pacc, const float* __restrict__ lpart,
    float* __restrict__ out) {
  const int i = blockIdx.x;
  const int c = threadIdx.x;
  const int h = c >> 6;
  float l = 0.f, s = 0.f;
#pragma unroll
  for (int sp = 0; sp < JSPLIT; ++sp) {
    l += lpart[((size_t)sp * N_NODES + i) * NH + h];
    s += pacc[((size_t)sp * N_NODES + i) * C + c];
  }
  out[(size_t)i * C + c] = s / l;
}

extern "C" void kernel_launch(void* const* d_in, const int* in_sizes, int n_in,
                              void* d_out, int out_size, void* d_ws, size_t ws_size,
                              hipStream_t stream) {
  const float* nf  = (const float*)d_in[0];
  const int* adj   = (const int*)d_in[1];
  const float* W   = (const float*)d_in[2];
  const float* bias = (const float*)d_in[3];
  const float* av  = (const float*)d_in[4];
  float* out = (float*)d_out;

  char* ws = (char*)d_ws;
  unsigned short* featsT = (unsigned short*)ws;                       // 2 MB
  float* dstT  = (float*)(ws + (2u << 20));                           // 64 KB
  float* srcv  = (float*)(ws + (2u << 20) + (64u << 10));             // 64 KB
  float* lpart = (float*)(ws + (2u << 20) + (128u << 10));            // 256 KB
  float* pacc  = (float*)(ws + (2u << 20) + (384u << 10));            // 16 MB

  k_feats<<<N_NODES / ROWS, 256, 0, stream>>>(nf, W, bias, av, featsT, srcv, dstT);
  dim3 g2(JSPLIT, N_NODES / TI);
  k_attn<<<g2, 256, 0, stream>>>(adj, featsT, srcv, dstT, pacc, lpart);
  k_final<<<N_NODES, 256, 0, stream>>>(pacc, lpart, out);
}